// Round 9
// baseline (81.236 us; speedup 1.0000x reference)
//
#include <hip/hip_runtime.h>

#define HH 1024
#define WW 1024
#define NS 16
#define RB 2                    // rows per fused block (occupancy lever)

typedef float f32x4 __attribute__((ext_vector_type(4)));

// ---------------------------------------------------------------------------
// Pass 1 (fused): one block per (RB rows, sample).
//  - preload RB mask f32x4 + 3*RB img f32x4 per thread (all loads in flight)
//  - minimal pre-barrier work: pack bits (3 shfls/row) -> LDS
//  - select + nontemporal-store the speculative IDENTITY result
//  - row min/max stats computed AFTER stores (hidden under store drain)
// Non-identity crops are rewritten by the tail kernel.
// ---------------------------------------------------------------------------
__global__ __launch_bounds__(256)
void fused_kernel(const float* __restrict__ mask,
                  const float* __restrict__ img,
                  int* __restrict__ rowMinC,
                  int* __restrict__ rowMaxC,
                  float* __restrict__ out) {
    const int s  = blockIdx.y;
    const int r0 = blockIdx.x * RB;
    const int t  = threadIdx.x;

    const f32x4* m4 = (const f32x4*)(mask + (size_t)s * HH * WW);
    const f32x4* ip = (const f32x4*)(img + ((size_t)s * HH + r0) * WW * 3);
    f32x4*       op = (f32x4*)(out + ((size_t)s * HH + r0) * WW * 3);

    // ---- issue ALL loads first (maximum memory-level parallelism) ----
    f32x4 mv[RB];
#pragma unroll
    for (int rr = 0; rr < RB; ++rr)
        mv[rr] = __builtin_nontemporal_load(&m4[(size_t)(r0 + rr) * 256 + t]);

    f32x4 iv[RB][3];
#pragma unroll
    for (int rr = 0; rr < RB; ++rr)
#pragma unroll
        for (int j = 0; j < 3; ++j)
            iv[rr][j] = __builtin_nontemporal_load(&ip[(size_t)rr * 768 + t + (j << 8)]);

    // ---- minimal mask phase: pack bits only (3 shfls/row) ----
    __shared__ unsigned int pw[RB][32];

#pragma unroll
    for (int rr = 0; rr < RB; ++rr) {
        unsigned int w = (mv[rr].x >= 0.5f ? 1u : 0u)
                       | (mv[rr].y >= 0.5f ? 2u : 0u)
                       | (mv[rr].z >= 0.5f ? 4u : 0u)
                       | (mv[rr].w >= 0.5f ? 8u : 0u);
        w |= __shfl_down(w, 1) << 4;
        w |= __shfl_down(w, 2) << 8;
        w |= __shfl_down(w, 4) << 16;
        if ((t & 7) == 0) pw[rr][t >> 3] = w;
    }
    __syncthreads();

    // ---- select + store (img already in registers) ----
#pragma unroll
    for (int rr = 0; rr < RB; ++rr) {
        const unsigned int* pwr = pw[rr];
#pragma unroll
        for (int j = 0; j < 3; ++j) {
            int fi = t + (j << 8);          // f32x4 index in row, 0..767
            int F  = fi << 2;               // float offset in row
            int p0 = F / 3;                 // first pixel covered
            int r  = F - p0 * 3;            // 0..2
            unsigned int b0 = (pwr[p0 >> 5] >> (p0 & 31)) & 1u;
            int p1 = p0 + 1;
            unsigned int b1 = (pwr[p1 >> 5] >> (p1 & 31)) & 1u;
            f32x4 v = iv[rr][j];
            f32x4 o;
            o.x = b0 ? v.x : 0.0f;
            o.y = ((r < 2) ? b0 : b1) ? v.y : 0.0f;
            o.z = ((r == 0) ? b0 : b1) ? v.z : 0.0f;
            o.w = b1 ? v.w : 0.0f;
            __builtin_nontemporal_store(o, &op[(size_t)rr * 768 + fi]);
        }
    }

    // ---- row stats from packed words (hidden under store drain) ----
    // wave wv (0..RB-1), lanes 0..31: word l of row wv.
    const int wv = t >> 6;
    const int l  = t & 63;
    if (wv < RB && l < 32) {
        unsigned int w = pw[wv][l];
        int cmin = w ? (l << 5) + __builtin_ctz(w)        : WW;
        int cmax = w ? (l << 5) + 31 - __builtin_clz(w)   : -1;
        // reduce-to-lane0 over 32 lanes; upper-lane garbage never reaches lane 0
        for (int off = 16; off > 0; off >>= 1) {
            cmin = min(cmin, __shfl_down(cmin, off));
            cmax = max(cmax, __shfl_down(cmax, off));
        }
        if (l == 0) {
            rowMinC[s * HH + r0 + wv] = cmin;
            rowMaxC[s * HH + r0 + wv] = cmax;
        }
    }
}

// ---------------------------------------------------------------------------
// Pass 2 (tail): one block per sample. Reduce row stats -> crop params.
// Identity crop (the speculated case) -> return. Otherwise rewrite the whole
// sample with the general bilinear path (correctness fallback).
// ---------------------------------------------------------------------------
__global__ __launch_bounds__(256)
void tail_kernel(const float* __restrict__ mask,
                 const float* __restrict__ img,
                 const int* __restrict__ rowMinC,
                 const int* __restrict__ rowMaxC,
                 float* __restrict__ out) {
    const int s = blockIdx.x;
    const int t = threadIdx.x;

    int minR = HH, maxR = -1, minC = WW, maxC = -1;
#pragma unroll
    for (int m = 0; m < HH / 256; ++m) {
        int r = t + (m << 8);
        int mc = rowMaxC[s * HH + r];
        if (mc >= 0) {
            minR = min(minR, r);
            maxR = max(maxR, r);
            minC = min(minC, rowMinC[s * HH + r]);
            maxC = max(maxC, mc);
        }
    }
    for (int off = 32; off > 0; off >>= 1) {
        minR = min(minR, __shfl_down(minR, off));
        maxR = max(maxR, __shfl_down(maxR, off));
        minC = min(minC, __shfl_down(minC, off));
        maxC = max(maxC, __shfl_down(maxC, off));
    }
    __shared__ int sm[4][4];
    __shared__ int bc[3];
    int wave = t >> 6, lane = t & 63;
    if (lane == 0) { sm[wave][0] = minR; sm[wave][1] = maxR; sm[wave][2] = minC; sm[wave][3] = maxC; }
    __syncthreads();
    if (t == 0) {
        for (int wv = 1; wv < 4; ++wv) {
            minR = min(minR, sm[wv][0]);
            maxR = max(maxR, sm[wv][1]);
            minC = min(minC, sm[wv][2]);
            maxC = max(maxC, sm[wv][3]);
        }
        int xl, xr, yl, yr;
        if (maxR < 0) { xl = 0; xr = HH; } else { xl = max(minR - 1, 0); xr = maxR + 1; }
        if (maxC < 0) { yl = 0; yr = WW; } else { yl = max(minC - 1, 0); yr = maxC + 1; }
        int h = xr - xl, w = yr - yl;
        int c = min(h, w);
        bc[0] = c;
        bc[1] = xl + (h - c) / 2;
        bc[2] = yl + (w - c) / 2;
    }
    __syncthreads();
    const int c = bc[0], hstart = bc[1], wstart = bc[2];
    if (c == HH && hstart == 0 && wstart == 0) return;   // speculation was exact

    // General bilinear rewrite of the whole sample (rare fallback path).
    const float* msk = mask + (size_t)s * HH * WW;
    const float* im  = img  + (size_t)s * HH * WW * 3;
    float*       ob  = out  + (size_t)s * HH * WW * 3;

    float cf = (float)c;
    float sy = cf / (float)HH;
    float sx = cf / (float)WW;

    for (int row = 0; row < HH; ++row) {
        float ysf = fminf(fmaxf((row + 0.5f) * sy - 0.5f, 0.0f), cf - 1.0f);
        int   y0i = (int)floorf(ysf);
        float wy  = ysf - (float)y0i;
        int   ry0 = hstart + y0i;
        int   ry1 = min(ry0 + 1, hstart + c - 1);
        float* orow = ob + (size_t)row * WW * 3;

        for (int k = 0; k < 4; ++k) {
            int ox = (t << 2) + k;
            float xsf = fminf(fmaxf((ox + 0.5f) * sx - 0.5f, 0.0f), cf - 1.0f);
            int   x0i = (int)floorf(xsf);
            float wx  = xsf - (float)x0i;
            int   rx0 = wstart + x0i;
            int   rx1 = min(rx0 + 1, wstart + c - 1);

            float p00[3], p01[3], p10[3], p11[3];
            auto fetch = [&](int y, int x, float* p) {
                int idx = y * WW + x;
                float mv = msk[idx];
                if (mv >= 0.5f) {
                    const float* q = im + (size_t)idx * 3;
                    p[0] = q[0]; p[1] = q[1]; p[2] = q[2];
                } else {
                    p[0] = 0.0f; p[1] = 0.0f; p[2] = 0.0f;
                }
            };
            fetch(ry0, rx0, p00);
            fetch(ry0, rx1, p01);
            fetch(ry1, rx0, p10);
            fetch(ry1, rx1, p11);

            float* o = orow + (size_t)ox * 3;
#pragma unroll
            for (int ch = 0; ch < 3; ++ch) {
                float top = (1.0f - wx) * p00[ch] + wx * p01[ch];
                float bot = (1.0f - wx) * p10[ch] + wx * p11[ch];
                o[ch] = (1.0f - wy) * top + wy * bot;
            }
        }
    }
}

extern "C" void kernel_launch(void* const* d_in, const int* in_sizes, int n_in,
                              void* d_out, int out_size, void* d_ws, size_t ws_size,
                              hipStream_t stream) {
    const float* masks  = (const float*)d_in[0];
    const float* images = (const float*)d_in[1];
    float* out = (float*)d_out;

    int* rowMinC = (int*)d_ws;                 // NS*HH ints
    int* rowMaxC = rowMinC + NS * HH;          // NS*HH ints

    fused_kernel<<<dim3(HH / RB, NS), 256, 0, stream>>>(masks, images, rowMinC, rowMaxC, out);
    tail_kernel <<<NS,                256, 0, stream>>>(masks, images, rowMinC, rowMaxC, out);
}